// Round 4
// baseline (1191.045 us; speedup 1.0000x reference)
//
#include <hip/hip_runtime.h>
#include <math.h>

#define CIN  256
#define MEDC 128
#define KOUT 128
#define HWSZ 6400   // 80*80
#define NB   16
#define TP   16     // pixels per block

typedef unsigned long long u64;
typedef u64 u64x2 __attribute__((ext_vector_type(2)));

// Bit-exact emulation of numpy's SIMD float32 exp (Cephes expf with FMA,
// quadrant via round-to-nearest-even of single-rounded x*log2e, 2^q exact).
__device__ __forceinline__ float numpy_expf(float x) {
#pragma clang fp contract(off)
    const float q = __builtin_rintf(x * 1.44269504088896341f);   // NPY_LOG2Ef
    float r = __builtin_fmaf(q, -0.693359375f, x);               // Cody-Waite hi
    r = __builtin_fmaf(q, 2.12194440e-4f, r);                    // Cody-Waite lo
    float p = __builtin_fmaf(1.9875691500e-4f, r, 1.3981999507e-3f);
    p = __builtin_fmaf(p, r, 8.3334519073e-3f);
    p = __builtin_fmaf(p, r, 4.1665795894e-2f);
    p = __builtin_fmaf(p, r, 1.6666665459e-1f);
    p = __builtin_fmaf(p, r, 5.0000001201e-1f);
    const float r2 = r * r;
    p = __builtin_fmaf(p, r2, r);    // literal Cephes: y = y*z + x
    p = p + 1.0f;                    // then y += 1
    return __builtin_ldexpf(p, (int)q);   // exact scale, |q| small here
}

// Transpose weights (fp32) for coalesced loads in the chain GEMMs.
__global__ void prep_T(const float* __restrict__ w1, const float* __restrict__ w2,
                       float* __restrict__ w1t, float* __restrict__ w2t) {
    const int c = blockIdx.x;    // 256
    const int m = threadIdx.x;   // 128
    w1t[c * MEDC + m] = w1[m * CIN + c];
    w2t[m * CIN + c]  = w2[c * MEDC + m];
}

__global__ __launch_bounds__(256, 2)
void csel_main(const float* __restrict__ x,
               const float* __restrict__ w1t, const float* __restrict__ w2t,
               const float* __restrict__ b1, const float* __restrict__ b2,
               float* __restrict__ out) {
    __shared__ __align__(16) float xs[CIN * 20];    // 20 KB  x tile (stride 20)
    __shared__ __align__(16) float hs[MEDC * 20];   // 10 KB  h (ref-exact fp32 bits)
    __shared__ __align__(16) u64  keys[TP * CIN];   // 32 KB

    const int t    = threadIdx.x;
    const int pix0 = blockIdx.x * TP;
    const int b    = pix0 / HWSZ;
    const int hw0  = pix0 % HWSZ;
    const float* xb = x + (size_t)b * CIN * HWSZ + hw0;

    // ---- stage x tile: 256 channels x 16 pixels ----
    {
        const int p  = t & (TP - 1);
        const int c0 = t >> 4;
        #pragma unroll
        for (int i = 0; i < 16; ++i) {
            const int c = c0 + i * 16;
            xs[c * 20 + p] = xb[(size_t)c * HWSZ + p];
        }
    }
    __syncthreads();

    // ---- GEMM1: h[m][p] = sequential fp32 FMA chain over c ascending ----
    // (matches numpy einsum axpy inner loop: out[hw] += w1[m,c]*x[c,hw])
    const int ml = (t & 63) * 2;   // two m values
    const int pg = t >> 6;         // four pixels pg*4..pg*4+3
    float a1[2][4] = {{0.f,0.f,0.f,0.f},{0.f,0.f,0.f,0.f}};

    #pragma unroll 4
    for (int c = 0; c < CIN; ++c) {
        const float2 wv = *(const float2*)&w1t[c * MEDC + ml];
        const float4 xv = *(const float4*)&xs[c * 20 + pg * 4];
        a1[0][0] = fmaf(wv.x, xv.x, a1[0][0]);
        a1[0][1] = fmaf(wv.x, xv.y, a1[0][1]);
        a1[0][2] = fmaf(wv.x, xv.z, a1[0][2]);
        a1[0][3] = fmaf(wv.x, xv.w, a1[0][3]);
        a1[1][0] = fmaf(wv.y, xv.x, a1[1][0]);
        a1[1][1] = fmaf(wv.y, xv.y, a1[1][1]);
        a1[1][2] = fmaf(wv.y, xv.z, a1[1][2]);
        a1[1][3] = fmaf(wv.y, xv.w, a1[1][3]);
    }
    #pragma unroll
    for (int i = 0; i < 2; ++i) {
        const float bi = b1[ml + i];
        #pragma unroll
        for (int j = 0; j < 4; ++j)
            hs[(ml + i) * 20 + pg * 4 + j] = a1[i][j] + bi;   // fp32 add
    }
    __syncthreads();

    // ---- GEMM2: x_[c=t][p] = sequential fp32 FMA chain over m ascending ----
    float a2[TP];
    #pragma unroll
    for (int j = 0; j < TP; ++j) a2[j] = 0.f;

    #pragma unroll 2
    for (int m = 0; m < MEDC; ++m) {
        const float wv = w2t[m * CIN + t];       // coalesced, L2-resident
        const float* hr = &hs[m * 20];           // wave-broadcast reads
        #pragma unroll
        for (int j = 0; j < TP; ++j)
            a2[j] = fmaf(wv, hr[j], a2[j]);
    }
    float xv32[TP];
    {
        const float bi = b2[t];
        #pragma unroll
        for (int j = 0; j < TP; ++j)
            xv32[j] = a2[j] + bi;                // fp32 add
    }

    // ---- sigmoid: s = 1/(1 + numpy_expf(-x_)), all fp32 ops ----
    #pragma unroll
    for (int p = 0; p < TP; ++p) {
#pragma clang fp contract(off)
        const float e = numpy_expf(-xv32[p]);
        const float d = 1.0f + e;                // fp32 add
        const float s = 1.0f / d;                // IEEE fp32 divide
        // descending score, ties -> lower channel index first (stable)
        keys[p * CIN + t] = ((u64)__float_as_uint(s) << 8) | (u64)(255 - t);
    }
    __syncthreads();

    // ---- rank by comparison counting; write out[rank] = x * x_ ----
    float* ob = out + (size_t)b * KOUT * HWSZ + hw0;
    for (int p = 0; p < TP; ++p) {
        const u64 kc = keys[p * CIN + t];
        int rank = 0;
        #pragma unroll 4
        for (int j = 0; j < CIN; j += 2) {
            const u64x2 kk = *(const u64x2*)&keys[p * CIN + j];  // broadcast b128
            rank += (kk.x > kc) ? 1 : 0;
            rank += (kk.y > kc) ? 1 : 0;
        }
        if (rank < KOUT) {
            ob[(size_t)rank * HWSZ + p] = xs[t * 20 + p] * xv32[p];
        }
    }
}

extern "C" void kernel_launch(void* const* d_in, const int* in_sizes, int n_in,
                              void* d_out, int out_size, void* d_ws, size_t ws_size,
                              hipStream_t stream) {
    const float* x  = (const float*)d_in[0];
    const float* w1 = (const float*)d_in[1];
    const float* b1 = (const float*)d_in[2];
    const float* w2 = (const float*)d_in[3];
    const float* b2 = (const float*)d_in[4];
    // d_in[5] = out_c (always 128 per setup; hardcoded as KOUT)

    float* w1t = (float*)d_ws;              // 256*128 fp32 = 128 KB
    float* w2t = w1t + CIN * MEDC;          // 128*256 fp32 = 128 KB

    prep_T<<<CIN, MEDC, 0, stream>>>(w1, w2, w1t, w2t);
    csel_main<<<(NB * HWSZ) / TP, 256, 0, stream>>>(x, w1t, w2t, b1, b2, (float*)d_out);
}

// Round 5
// 737.221 us; speedup vs baseline: 1.6156x; 1.6156x over previous
//
#include <hip/hip_runtime.h>
#include <math.h>

#define CIN  256
#define MEDC 128
#define KOUT 128
#define HWSZ 6400   // 80*80
#define NB   16
#define TP   16     // pixels per block
#define KST  260    // keys row stride in u64 (2080 B ≡ 8 banks offset/row)

typedef unsigned long long u64;
typedef u64 u64x2 __attribute__((ext_vector_type(2)));

// Bit-exact emulation of numpy's SIMD float32 exp (Cephes expf with FMA).
__device__ __forceinline__ float numpy_expf(float x) {
#pragma clang fp contract(off)
    const float q = __builtin_rintf(x * 1.44269504088896341f);
    float r = __builtin_fmaf(q, -0.693359375f, x);
    r = __builtin_fmaf(q, 2.12194440e-4f, r);
    float p = __builtin_fmaf(1.9875691500e-4f, r, 1.3981999507e-3f);
    p = __builtin_fmaf(p, r, 8.3334519073e-3f);
    p = __builtin_fmaf(p, r, 4.1665795894e-2f);
    p = __builtin_fmaf(p, r, 1.6666665459e-1f);
    p = __builtin_fmaf(p, r, 5.0000001201e-1f);
    const float r2 = r * r;
    p = __builtin_fmaf(p, r2, r);
    p = p + 1.0f;
    return __builtin_ldexpf(p, (int)q);
}

__global__ void prep_T(const float* __restrict__ w1, const float* __restrict__ w2,
                       float* __restrict__ w1t, float* __restrict__ w2t) {
    const int c = blockIdx.x;    // 256
    const int m = threadIdx.x;   // 128
    w1t[c * MEDC + m] = w1[m * CIN + c];
    w2t[m * CIN + c]  = w2[c * MEDC + m];
}

__global__ __launch_bounds__(256, 3)
void csel_main(const float* __restrict__ x,
               const float* __restrict__ w1t, const float* __restrict__ w2t,
               const float* __restrict__ b1, const float* __restrict__ b2,
               float* __restrict__ out) {
    // xs: x tile (stride 20), later overwritten in-place with prod = x * x_
    __shared__ __align__(16) float xs[CIN * 20];        // 20480 B
    // keys region; hs aliases its first 10240 B (dead once GEMM2 reads finish)
    __shared__ __align__(16) u64 keys[TP * KST];        // 33280 B  (total 53760 -> 3 blk/CU)
    float* hs = (float*)keys;                           // [MEDC * 20]

    const int t    = threadIdx.x;
    const int pix0 = blockIdx.x * TP;
    const int b    = pix0 / HWSZ;
    const int hw0  = pix0 % HWSZ;
    const float* xb = x + (size_t)b * CIN * HWSZ + hw0;

    // ---- stage x tile: 256 channels x 16 pixels ----
    {
        const int p  = t & (TP - 1);
        const int c0 = t >> 4;
        #pragma unroll
        for (int i = 0; i < 16; ++i) {
            const int c = c0 + i * 16;
            xs[c * 20 + p] = xb[(size_t)c * HWSZ + p];
        }
    }
    __syncthreads();

    // ---- GEMM1: h[m][p] = sequential fp32 FMA chain over c ascending ----
    const int ml = (t & 63) * 2;
    const int pg = t >> 6;
    float a1[2][4] = {{0.f,0.f,0.f,0.f},{0.f,0.f,0.f,0.f}};

    #pragma unroll 4
    for (int c = 0; c < CIN; ++c) {
        const float2 wv = *(const float2*)&w1t[c * MEDC + ml];
        const float4 xv = *(const float4*)&xs[c * 20 + pg * 4];
        a1[0][0] = fmaf(wv.x, xv.x, a1[0][0]);
        a1[0][1] = fmaf(wv.x, xv.y, a1[0][1]);
        a1[0][2] = fmaf(wv.x, xv.z, a1[0][2]);
        a1[0][3] = fmaf(wv.x, xv.w, a1[0][3]);
        a1[1][0] = fmaf(wv.y, xv.x, a1[1][0]);
        a1[1][1] = fmaf(wv.y, xv.y, a1[1][1]);
        a1[1][2] = fmaf(wv.y, xv.z, a1[1][2]);
        a1[1][3] = fmaf(wv.y, xv.w, a1[1][3]);
    }
    __syncthreads();   // ensure all GEMM1 xs reads done before hs (alias-safe) writes? hs!=xs, but keep order: hs writes follow
    #pragma unroll
    for (int i = 0; i < 2; ++i) {
        const float bi = b1[ml + i];
        #pragma unroll
        for (int j = 0; j < 4; ++j)
            hs[(ml + i) * 20 + pg * 4 + j] = a1[i][j] + bi;
    }
    __syncthreads();

    // ---- GEMM2: x_[c=t][p] = sequential fp32 FMA chain over m ascending ----
    float a2[TP];
    #pragma unroll
    for (int j = 0; j < TP; ++j) a2[j] = 0.f;

    #pragma unroll 2
    for (int m = 0; m < MEDC; ++m) {
        const float wv = w2t[m * CIN + t];
        const float* hr = &hs[m * 20];
        #pragma unroll
        for (int j = 0; j < TP; ++j)
            a2[j] = fmaf(wv, hr[j], a2[j]);
    }
    float xv32[TP];
    {
        const float bi = b2[t];
        #pragma unroll
        for (int j = 0; j < TP; ++j)
            xv32[j] = a2[j] + bi;
    }
    __syncthreads();   // all hs reads complete before keys overwrite region

    // ---- sigmoid -> keys; prod = x * x_ in-place over xs (row t exclusive) ----
    #pragma unroll
    for (int p = 0; p < TP; ++p) {
#pragma clang fp contract(off)
        const float e = numpy_expf(-xv32[p]);
        const float d = 1.0f + e;
        const float s = 1.0f / d;
        keys[p * KST + t] = ((u64)__float_as_uint(s) << 8) | (u64)(255 - t);
        xs[t * 20 + p] = xs[t * 20 + p] * xv32[p];
    }
    __syncthreads();

    // ---- rank: thread -> pixel p = t>>4, channels c = (t&15) + 16*i ----
    const int p   = t >> 4;
    const int l16 = t & 15;
    const u64* kp = &keys[p * KST];

    u64 kc[16];
    #pragma unroll
    for (int i = 0; i < 16; ++i) kc[i] = kp[l16 + 16 * i];
    int rank[16];
    #pragma unroll
    for (int i = 0; i < 16; ++i) rank[i] = 0;

    #pragma unroll 2
    for (int j = 0; j < CIN; j += 4) {
        const u64x2 ka = *(const u64x2*)&kp[j];
        const u64x2 kb = *(const u64x2*)&kp[j + 2];
        #pragma unroll
        for (int i = 0; i < 16; ++i) {
            rank[i] += (ka.x > kc[i]) ? 1 : 0;
            rank[i] += (ka.y > kc[i]) ? 1 : 0;
            rank[i] += (kb.x > kc[i]) ? 1 : 0;
            rank[i] += (kb.y > kc[i]) ? 1 : 0;
        }
    }

    // ---- epilogue: out[rank][pixel] = prod ----
    float* ob = out + (size_t)b * KOUT * HWSZ + hw0 + p;
    #pragma unroll
    for (int i = 0; i < 16; ++i) {
        const int c = l16 + 16 * i;
        if (rank[i] < KOUT)
            ob[(size_t)rank[i] * HWSZ] = xs[c * 20 + p];
    }
}

extern "C" void kernel_launch(void* const* d_in, const int* in_sizes, int n_in,
                              void* d_out, int out_size, void* d_ws, size_t ws_size,
                              hipStream_t stream) {
    const float* x  = (const float*)d_in[0];
    const float* w1 = (const float*)d_in[1];
    const float* b1 = (const float*)d_in[2];
    const float* w2 = (const float*)d_in[3];
    const float* b2 = (const float*)d_in[4];

    float* w1t = (float*)d_ws;              // 128 KB
    float* w2t = w1t + CIN * MEDC;          // 128 KB

    prep_T<<<CIN, MEDC, 0, stream>>>(w1, w2, w1t, w2t);
    csel_main<<<(NB * HWSZ) / TP, 256, 0, stream>>>(x, w1t, w2t, b1, b2, (float*)d_out);
}